// Round 6
// baseline (278.115 us; speedup 1.0000x reference)
//
#include <hip/hip_runtime.h>

typedef __attribute__((ext_vector_type(8))) short          bf16x8;
typedef __attribute__((ext_vector_type(8))) unsigned short u16x8;
typedef __attribute__((ext_vector_type(4))) unsigned short u16x4;
typedef __attribute__((ext_vector_type(4))) float          f32x4;
typedef __attribute__((ext_vector_type(4))) unsigned int   u32x4;

union U8 { u16x8 u; bf16x8 b; u32x4 w; };
union U4 { u16x4 u; unsigned w[2]; };

__device__ __forceinline__ unsigned short f2bf(float f){
  unsigned u = __float_as_uint(f);
  return (unsigned short)((u + 0x7fffu + ((u >> 16) & 1u)) >> 16);
}
// pack two floats to bf16x2 (round-half-up): lo->low16, hi->high16. exact 0 preserved.
__device__ __forceinline__ unsigned pack_bf16(float lo, float hi){
  unsigned a = __float_as_uint(hi) + 0x8000u;
  unsigned b = __float_as_uint(lo) + 0x8000u;
  return __builtin_amdgcn_perm(a, b, 0x07060302u);
}
// max-pair -> packed bf16 (RNE) -> halfword mask (0xFFFF/0x0000 halves).
__device__ __forceinline__ unsigned maskpack(float e0, float e1, unsigned m){
  unsigned r;
  asm("v_cvt_pk_bf16_f32 %0, %1, %2" : "=v"(r) : "v"(e0), "v"(e1));
  return r & m;
}

#define NN  1024
#define FIN 256
#define NH  8
#define FO  64

// ---------------------------------------------------------------------------
// prep: wfrag = w in MFMA-B-frag layout; Abits = bit-packed A (b-affine:
// XCD b packs batch b's rows); cnt = merge tickets zeroed.
// grid 1024 x 256, 4 blocks/CU, pure streaming (33.5 MB A at HBM BW ~7us;
// R5 lesson: this read inside 2-blocks/CU stageA was latency-bound).
// ---------------------------------------------------------------------------
__global__ __launch_bounds__(256) void prep(
    const float* __restrict__ w, const int* __restrict__ A,
    unsigned short* __restrict__ wfrag, unsigned long long* __restrict__ Abits,
    int* __restrict__ cnt)
{
  const int bid = blockIdx.x, t = threadIdx.x;
  const int tid = bid * 256 + t;
  if (tid < 128) cnt[tid] = 0;
  if (tid < 16384){
    const int lane = tid & 63, ss = (tid >> 6) & 3, kc = (tid >> 8) & 7, h = tid >> 11;
    const int o = 16 * ss + (lane & 15);
    const int f = kc * 32 + (lane >> 4) * 8;
    u16x8 r;
    #pragma unroll
    for (int j = 0; j < 8; j++) r[j] = f2bf(w[(h * FIN + f + j) * FO + o]);
    *(u16x8*)(wfrag + tid * 8) = r;
  }
  // adjacency bit-pack: block handles 8192 ints of batch b = bid&7
  const int base = (bid & 7) * 1048576 + (bid >> 3) * 8192;
  #pragma unroll 4
  for (int k = 0; k < 32; k++){
    const int i = base + k * 256 + t;
    unsigned long long m = __ballot(A[i] > 0);
    if ((t & 63) == 0) Abits[i >> 6] = m;
  }
}

// ---------------------------------------------------------------------------
// Stage A: recx built in LDS per 16-row tile; h = recx @ w (MFMA);
// panel stores hT[b,h,mtile,o,32] + exp tables (R = exp(0.8 s), Ed, Ed2).
// Re-tiled vs R5: 1024 blocks x 256 thr (4 waves = 4 heads, hg picks head
// half) = 4 blocks/CU, 2x the wave pool of the old 512x512 config (R5 was
// 2 blocks/CU, latency-bound). rex tile built twice (once per hg) - cheap.
// XCD-affine: b = fid&7, so hT/tables land in the L2 that stageB reads.
// ---------------------------------------------------------------------------
__global__ __launch_bounds__(256, 4) void gemmA(
    const float* __restrict__ x, const float* __restrict__ e_at,
    const float* __restrict__ Np, const unsigned short* __restrict__ wfrag,
    const float* __restrict__ a_src, const float* __restrict__ a_dst,
    unsigned short* __restrict__ hT,
    float* __restrict__ Rt, float* __restrict__ expd, float* __restrict__ expd2)
{
  __shared__ unsigned short rex[16 * 264];   // 16 rows x 256 f, pad 264
  const int t = threadIdx.x;
  const int fid = blockIdx.x;
  const int b = fid & 7, tile = (fid >> 3) & 63, hg = fid >> 9;
  const int n0 = tile * 16;

  {                                          // cooperative recx tile build (x2)
    #pragma unroll
    for (int rep = 0; rep < 2; rep++){
      const int row = rep * 8 + (t >> 5), f0 = (t & 31) * 8;
      const int nrow = n0 + row;
      const float* ep = e_at + (b * NN + nrow) * FIN + f0;
      const float* qp = Np + nrow * FIN + f0;
      const float* xp = x + b * FIN + f0;
      f32x4 e0 = *(const f32x4*)ep, e1 = *(const f32x4*)(ep + 4);
      f32x4 q0 = *(const f32x4*)qp, q1 = *(const f32x4*)(qp + 4);
      f32x4 x0 = *(const f32x4*)xp, x1 = *(const f32x4*)(xp + 4);
      u16x8 r;
      #pragma unroll
      for (int j = 0; j < 4; j++){
        r[j]     = f2bf(e0[j] * q0[j] * x0[j]);
        r[j + 4] = f2bf(e1[j] * q1[j] * x1[j]);
      }
      *(u16x8*)(rex + row * 264 + f0) = r;
    }
  }
  __syncthreads();

  const int h = hg * 4 + (t >> 6), lane = t & 63, quad = lane >> 4, l15 = lane & 15;
  const unsigned short* wf = wfrag + h * 16384 + lane * 8;

  f32x4 acc[4] = {};
  #pragma unroll
  for (int kc = 0; kc < 8; kc++){
    U8 a0, bf[4];
    a0.u = *(const u16x8*)(rex + l15 * 264 + kc * 32 + quad * 8);
    #pragma unroll
    for (int ss = 0; ss < 4; ss++) bf[ss].u = *(const u16x8*)(wf + (kc * 4 + ss) * 512);
    #pragma unroll
    for (int ss = 0; ss < 4; ss++)
      acc[ss] = __builtin_amdgcn_mfma_f32_16x16x32_bf16(a0.b, bf[ss].b, acc[ss], 0, 0, 0);
  }

  // panel store: [b,h,mtile,o(64),m(32)], C/D row(n)=quad*4+i, col(o)=16ss+l15
  {
    const int mtile = tile >> 1, moff = (tile & 1) * 16;
    unsigned short* pan = hT + (size_t)(((b * NH + h) * 32 + mtile) * 64) * 32;
    #pragma unroll
    for (int ss = 0; ss < 4; ss++){
      U4 v;
      v.w[0] = pack_bf16(acc[ss][0], acc[ss][1]);
      v.w[1] = pack_bf16(acc[ss][2], acc[ss][3]);
      *(u16x4*)(pan + (16 * ss + l15) * 32 + moff + quad * 4) = v.u;
    }
  }

  // s/d reductions -> exp tables (R = exp(0.8 s): row factor exp(0.2 s) cancels
  // in softmax, so P' = max(R*Ed, Ed2) gives identical attention weights)
  float as4[4], ad4[4];
  #pragma unroll
  for (int ss = 0; ss < 4; ss++){
    as4[ss] = a_src[h * FO + 16 * ss + l15];
    ad4[ss] = a_dst[h * FO + 16 * ss + l15];
  }
  #pragma unroll
  for (int i = 0; i < 4; i++){
    float ps = 0.f, pd = 0.f;
    #pragma unroll
    for (int ss = 0; ss < 4; ss++){ ps += acc[ss][i] * as4[ss]; pd += acc[ss][i] * ad4[ss]; }
    #pragma unroll
    for (int off = 1; off < 16; off <<= 1){
      ps += __shfl_xor(ps, off);
      pd += __shfl_xor(pd, off);
    }
    if (l15 == 0){
      const int idx = (b * NH + h) * NN + n0 + quad * 4 + i;
      Rt[idx]    = __expf(0.8f * ps);
      expd[idx]  = __expf(pd);
      expd2[idx] = __expf(0.2f * pd);
    }
  }
}

// ---------------------------------------------------------------------------
// Stage B: fused masked-softmax aggregation + last-block head-merge epilogue.
// 1024 flat blocks of 256 thr; block = 1 head x 64 rows; 4 waves =
// 2 row-halves(rw) x 2 m-halves(mh); 32 rows x 512 cols per wave (2 row-groups
// in-register), 16 fully-unrolled iters (R2-proven inner loop).
// __launch_bounds__(256,4): 128 reg/wave budget (R3 lesson: (256,8) spills).
// XCD decode b=fid&7: panels+Abits+tables L2-resident (R2: FETCH 43->5MB).
// Epilogue: after hpart stores, ticket atomicAdd per (b,rt); the 8th arriving
// head-block performs the head mean + bias + mz for its 64 rows (reads are
// XCD-local; __threadfence release/acquire makes it correct regardless of
// XCD mapping). Replaces the separate stageC dispatch.
// ---------------------------------------------------------------------------
__global__ __launch_bounds__(256, 4) void attnB(
    const unsigned* __restrict__ Aw,
    const unsigned short* __restrict__ hT,
    const float* __restrict__ Rt,
    const float* __restrict__ expd, const float* __restrict__ expd2,
    float* __restrict__ hpart, int* __restrict__ cnt,
    const float* __restrict__ bias, const float* __restrict__ mz,
    float* __restrict__ out)
{
  // phase 1: smem[0..1023]=Ed, [1024..2047]=Ed2 (this head)
  // phase 2: smem[0..4159]=merge[64][65], smem[4160..4287]=den[2mh][64]
  __shared__ float smem[4288];
  __shared__ __align__(8) unsigned lut[16][2];   // nibble -> 2 halfword masks
  __shared__ int tick;

  const int fid = blockIdx.x;
  const int b = fid & 7, h = (fid >> 3) & 7, rt = fid >> 6;  // rt in [0,16)
  const int n0 = rt * 64;

  const int t = threadIdx.x;                     // 256
  const int w = t >> 6, lane = t & 63, quad = lane >> 4, l15 = lane & 15;
  const int rw = w & 1, mh = w >> 1;
  const int nb = n0 + rw * 32;                   // wave's 32-row base

  if (t < 16){
    lut[t][0] = (t & 1 ? 0xFFFFu : 0u) | (t & 2 ? 0xFFFF0000u : 0u);
    lut[t][1] = (t & 4 ? 0xFFFFu : 0u) | (t & 8 ? 0xFFFF0000u : 0u);
  }
  {                                      // exp-table preload (1 head, coalesced)
    const float* s1 = expd  + (b * NH + h) * NN;
    const float* s2 = expd2 + (b * NH + h) * NN;
    *(f32x4*)(smem + t * 4)        = *(const f32x4*)(s1 + t * 4);
    *(f32x4*)(smem + 1024 + t * 4) = *(const f32x4*)(s2 + t * 4);
  }
  __syncthreads();

  const int hb = (b * NH + h) * NN;
  const float Rv0 = Rt[hb + nb + l15];
  const float Rv1 = Rt[hb + nb + 16 + l15];
  const unsigned short* pb = hT + (size_t)(b * NH + h) * 65536 + l15 * 32 + quad * 8;
  const float* edh = smem + quad * 8;
  const float* e2h = smem + 1024 + quad * 8;
  const unsigned* awp = Aw + (b * NN + nb) * 32;
  const int c0 = mh * 16;
  const int qs = quad * 8;

  U8 pan[4];
  #pragma unroll
  for (int ss = 0; ss < 4; ss++)
    pan[ss].u = *(const u16x8*)(pb + (size_t)c0 * 2048 + ss * 512);
  unsigned mw0 = awp[l15 * 32 + c0];
  unsigned mw1 = awp[(16 + l15) * 32 + c0];

  U8 ones;                               // bf16 1.0 B-frag for row sums
  #pragma unroll
  for (int j = 0; j < 8; j++) ones.u[j] = 0x3F80;

  f32x4 acc0[4] = {}, acc1[4] = {};
  f32x4 accl0 = {}, accl1 = {};

  #pragma unroll
  for (int cc = 0; cc < 16; cc++){
    const int c = c0 + cc;
    // expand bit masks via LUT (mask words prefetched last iter)
    const unsigned am0 = (mw0 >> qs) & 0xFF;
    const unsigned am1 = (mw1 >> qs) & 0xFF;
    const uint2 la0 = *(const uint2*)&lut[am0 & 15][0];
    const uint2 lb0 = *(const uint2*)&lut[(am0 >> 4) & 15][0];
    const uint2 la1 = *(const uint2*)&lut[am1 & 15][0];
    const uint2 lb1 = *(const uint2*)&lut[(am1 >> 4) & 15][0];
    if (cc + 1 < 16){                    // mask prefetch from L2 (Abits)
      mw0 = awp[l15 * 32 + c + 1];
      mw1 = awp[(16 + l15) * 32 + c + 1];
    }
    // shared column factors (broadcast LDS reads, conflict-free)
    const f32x4 d01 = *(const f32x4*)(edh + c * 32);
    const f32x4 d23 = *(const f32x4*)(edh + c * 32 + 4);
    const f32x4 g01 = *(const f32x4*)(e2h + c * 32);
    const f32x4 g23 = *(const f32x4*)(e2h + c * 32 + 4);
    // P for row-group 0
    {
      const f32x4 p01 = Rv0 * d01, p23 = Rv0 * d23;
      U8 p;
      p.w[0] = maskpack(fmaxf(p01[0], g01[0]), fmaxf(p01[1], g01[1]), la0.x);
      p.w[1] = maskpack(fmaxf(p01[2], g01[2]), fmaxf(p01[3], g01[3]), la0.y);
      p.w[2] = maskpack(fmaxf(p23[0], g23[0]), fmaxf(p23[1], g23[1]), lb0.x);
      p.w[3] = maskpack(fmaxf(p23[2], g23[2]), fmaxf(p23[3], g23[3]), lb0.y);
      #pragma unroll
      for (int ss = 0; ss < 4; ss++)
        acc0[ss] = __builtin_amdgcn_mfma_f32_16x16x32_bf16(p.b, pan[ss].b, acc0[ss], 0, 0, 0);
      accl0 = __builtin_amdgcn_mfma_f32_16x16x32_bf16(p.b, ones.b, accl0, 0, 0, 0);
    }
    // P for row-group 1 (same pan frags -> panel traffic halved)
    {
      const f32x4 p01 = Rv1 * d01, p23 = Rv1 * d23;
      U8 p;
      p.w[0] = maskpack(fmaxf(p01[0], g01[0]), fmaxf(p01[1], g01[1]), la1.x);
      p.w[1] = maskpack(fmaxf(p01[2], g01[2]), fmaxf(p01[3], g01[3]), la1.y);
      p.w[2] = maskpack(fmaxf(p23[0], g23[0]), fmaxf(p23[1], g23[1]), lb1.x);
      p.w[3] = maskpack(fmaxf(p23[2], g23[2]), fmaxf(p23[3], g23[3]), lb1.y);
      #pragma unroll
      for (int ss = 0; ss < 4; ss++)
        acc1[ss] = __builtin_amdgcn_mfma_f32_16x16x32_bf16(p.b, pan[ss].b, acc1[ss], 0, 0, 0);
      accl1 = __builtin_amdgcn_mfma_f32_16x16x32_bf16(p.b, ones.b, accl1, 0, 0, 0);
    }
    if (cc + 1 < 16){                    // pan prefetch, 1-deep
      #pragma unroll
      for (int ss = 0; ss < 4; ss++)
        pan[ss].u = *(const u16x8*)(pb + (size_t)(c + 1) * 2048 + ss * 512);
    }
  }

  __syncthreads();                       // tables dead; smem becomes merge buffer

  // denominators: accl[i] = complete row sum over this wave's m-half,
  // replicated over l15. Distinct (mh,rw,row) slots -> no atomics.
  float* den = smem + 4160;
  if (l15 == 0){
    #pragma unroll
    for (int i = 0; i < 4; i++){
      den[mh * 64 + rw * 32 + quad * 4 + i]      = accl0[i];
      den[mh * 64 + rw * 32 + 16 + quad * 4 + i] = accl1[i];
    }
  }
  // mh=1 waves park their numerators in merge[64][65]
  if (mh == 1){
    #pragma unroll
    for (int i = 0; i < 4; i++){
      const int r0 = rw * 32 + quad * 4 + i;
      #pragma unroll
      for (int ss = 0; ss < 4; ss++){
        smem[r0 * 65 + ss * 16 + l15]        = acc0[ss][i];
        smem[(r0 + 16) * 65 + ss * 16 + l15] = acc1[ss][i];
      }
    }
  }
  __syncthreads();

  // mh=0 waves: add halves, normalize, plain coalesced store to hpart
  if (mh == 0){
    float* hp = hpart + ((size_t)(b * NH + h) * NN + nb) * FO;
    #pragma unroll
    for (int i = 0; i < 4; i++){
      const int r = quad * 4 + i;
      const float ia = 1.0f / (den[rw * 32 + r] + den[64 + rw * 32 + r]);
      const float ib = 1.0f / (den[rw * 32 + 16 + r] + den[64 + rw * 32 + 16 + r]);
      #pragma unroll
      for (int ss = 0; ss < 4; ss++){
        hp[(size_t)r * FO + ss * 16 + l15] =
            (acc0[ss][i] + smem[(rw * 32 + r) * 65 + ss * 16 + l15]) * ia;
        hp[(size_t)(16 + r) * FO + ss * 16 + l15] =
            (acc1[ss][i] + smem[(rw * 32 + 16 + r) * 65 + ss * 16 + l15]) * ib;
      }
    }
  }

  // ---- merge epilogue: 8th-arriving head-block of (b,rt) does the head mean
  __threadfence();                       // release hpart stores (device scope)
  __syncthreads();
  if (t == 0) tick = atomicAdd(&cnt[b * 16 + rt], 1);
  __syncthreads();
  if (tick == 7){
    __threadfence();                     // acquire other blocks' hpart stores
    #pragma unroll
    for (int k = 0; k < 4; k++){
      const int idx = k * 256 + t;       // 1024 f32x4 = 64 rows x 16
      const int row = idx >> 4, o4 = (idx & 15) * 4;
      const float* hp0 = hpart + ((size_t)(b * NH) * NN + n0 + row) * FO + o4;
      f32x4 s = {};
      #pragma unroll
      for (int hh = 0; hh < NH; hh++)
        s += *(const f32x4*)(hp0 + (size_t)hh * NN * FO);
      const f32x4 bv = *(const f32x4*)(bias + o4);
      const float m = mz[b * NN + n0 + row];
      f32x4 r;
      #pragma unroll
      for (int j = 0; j < 4; j++) r[j] = (0.125f * s[j] + bv[j]) * m;
      *(f32x4*)(out + (size_t)(b * NN + n0 + row) * FO + o4) = r;
    }
  }
}

extern "C" void kernel_launch(void* const* d_in, const int* in_sizes, int n_in,
                              void* d_out, int out_size, void* d_ws, size_t ws_size,
                              hipStream_t stream)
{
  (void)in_sizes; (void)n_in; (void)out_size; (void)ws_size;
  const float* x    = (const float*)d_in[0];
  const int*   A    = (const int*)d_in[1];
  const float* mz   = (const float*)d_in[2];
  const float* e_at = (const float*)d_in[4];
  const float* Np   = (const float*)d_in[5];
  const float* w    = (const float*)d_in[6];
  const float* asrc = (const float*)d_in[7];
  const float* adst = (const float*)d_in[8];
  const float* bias = (const float*)d_in[9];
  float* out = (float*)d_out;

  char* ws = (char*)d_ws;
  unsigned short* wfrag = (unsigned short*)ws;                     // 256 KB
  unsigned short* hT    = (unsigned short*)(ws + 262144);          // 8 MB
  float* Rt    = (float*)(ws + 8650752);                           // 256 KB
  float* expd  = (float*)(ws + 8912896);                           // 256 KB
  float* expd2 = (float*)(ws + 9175040);                           // 256 KB
  unsigned long long* Abits = (unsigned long long*)(ws + 9437184); // 1 MB
  float* hpart = (float*)(ws + 10485760);                          // 16.8 MB
  int*   cnt   = (int*)(ws + 27262976);                            // 512 B

  prep <<<dim3(1024), dim3(256), 0, stream>>>(w, A, wfrag, Abits, cnt);
  gemmA<<<dim3(1024), dim3(256), 0, stream>>>(x, e_at, Np, wfrag, asrc, adst,
                                              hT, Rt, expd, expd2);
  attnB<<<dim3(1024), dim3(256), 0, stream>>>((const unsigned*)Abits, hT,
                                              Rt, expd, expd2, hpart, cnt,
                                              bias, mz, out);
}

// Round 7
// 154.340 us; speedup vs baseline: 1.8020x; 1.8020x over previous
//
#include <hip/hip_runtime.h>

typedef __attribute__((ext_vector_type(8))) short          bf16x8;
typedef __attribute__((ext_vector_type(8))) unsigned short u16x8;
typedef __attribute__((ext_vector_type(4))) unsigned short u16x4;
typedef __attribute__((ext_vector_type(4))) float          f32x4;
typedef __attribute__((ext_vector_type(4))) unsigned int   u32x4;

union U8 { u16x8 u; bf16x8 b; u32x4 w; };
union U4 { u16x4 u; unsigned w[2]; };

__device__ __forceinline__ unsigned short f2bf(float f){
  unsigned u = __float_as_uint(f);
  return (unsigned short)((u + 0x7fffu + ((u >> 16) & 1u)) >> 16);
}
// pack two floats to bf16x2 (round-half-up): lo->low16, hi->high16. exact 0 preserved.
__device__ __forceinline__ unsigned pack_bf16(float lo, float hi){
  unsigned a = __float_as_uint(hi) + 0x8000u;
  unsigned b = __float_as_uint(lo) + 0x8000u;
  return __builtin_amdgcn_perm(a, b, 0x07060302u);
}
// max-pair -> packed bf16 (RNE) -> halfword mask (0xFFFF/0x0000 halves).
__device__ __forceinline__ unsigned maskpack(float e0, float e1, unsigned m){
  unsigned r;
  asm("v_cvt_pk_bf16_f32 %0, %1, %2" : "=v"(r) : "v"(e0), "v"(e1));
  return r & m;
}

#define NN  1024
#define FIN 256
#define NH  8
#define FO  64

// ---------------------------------------------------------------------------
// prep: wfrag = w in MFMA-B-frag layout; Abits = bit-packed A (b-affine:
// XCD b packs batch b's rows). grid 1024 x 256, 4 blocks/CU, pure streaming.
// (R5 lesson: the 33.5MB A read inside 2-blocks/CU stageA was latency-bound.)
// ---------------------------------------------------------------------------
__global__ __launch_bounds__(256) void prep(
    const float* __restrict__ w, const int* __restrict__ A,
    unsigned short* __restrict__ wfrag, unsigned long long* __restrict__ Abits)
{
  const int bid = blockIdx.x, t = threadIdx.x;
  const int tid = bid * 256 + t;
  if (tid < 16384){
    const int lane = tid & 63, ss = (tid >> 6) & 3, kc = (tid >> 8) & 7, h = tid >> 11;
    const int o = 16 * ss + (lane & 15);
    const int f = kc * 32 + (lane >> 4) * 8;
    u16x8 r;
    #pragma unroll
    for (int j = 0; j < 8; j++) r[j] = f2bf(w[(h * FIN + f + j) * FO + o]);
    *(u16x8*)(wfrag + tid * 8) = r;
  }
  // adjacency bit-pack: block handles 8192 ints of batch b = bid&7
  const int base = (bid & 7) * 1048576 + (bid >> 3) * 8192;
  #pragma unroll 4
  for (int k = 0; k < 32; k++){
    const int i = base + k * 256 + t;
    unsigned long long m = __ballot(A[i] > 0);
    if ((t & 63) == 0) Abits[i >> 6] = m;
  }
}

// ---------------------------------------------------------------------------
// Stage A: recx built in LDS per 16-row tile; h = recx @ w (MFMA);
// panel stores hT[b,h,mtile,o,32] + exp tables (R = exp(0.8 s), Ed, Ed2).
// 1024 blocks x 256 thr (4 waves = 4 heads, hg picks head half) = 4 blocks/CU,
// 2x the wave pool of the old 512x512 config (which ran 2 blocks/CU,
// latency-bound). rex tile built twice (once per hg) - cheap.
// XCD-affine: b = fid&7, so hT/tables land in the L2 that attnB reads.
// ---------------------------------------------------------------------------
__global__ __launch_bounds__(256, 4) void gemmA(
    const float* __restrict__ x, const float* __restrict__ e_at,
    const float* __restrict__ Np, const unsigned short* __restrict__ wfrag,
    const float* __restrict__ a_src, const float* __restrict__ a_dst,
    unsigned short* __restrict__ hT,
    float* __restrict__ Rt, float* __restrict__ expd, float* __restrict__ expd2)
{
  __shared__ unsigned short rex[16 * 264];   // 16 rows x 256 f, pad 264
  const int t = threadIdx.x;
  const int fid = blockIdx.x;
  const int b = fid & 7, tile = (fid >> 3) & 63, hg = fid >> 9;
  const int n0 = tile * 16;

  {                                          // cooperative recx tile build (x2)
    #pragma unroll
    for (int rep = 0; rep < 2; rep++){
      const int row = rep * 8 + (t >> 5), f0 = (t & 31) * 8;
      const int nrow = n0 + row;
      const float* ep = e_at + (b * NN + nrow) * FIN + f0;
      const float* qp = Np + nrow * FIN + f0;
      const float* xp = x + b * FIN + f0;
      f32x4 e0 = *(const f32x4*)ep, e1 = *(const f32x4*)(ep + 4);
      f32x4 q0 = *(const f32x4*)qp, q1 = *(const f32x4*)(qp + 4);
      f32x4 x0 = *(const f32x4*)xp, x1 = *(const f32x4*)(xp + 4);
      u16x8 r;
      #pragma unroll
      for (int j = 0; j < 4; j++){
        r[j]     = f2bf(e0[j] * q0[j] * x0[j]);
        r[j + 4] = f2bf(e1[j] * q1[j] * x1[j]);
      }
      *(u16x8*)(rex + row * 264 + f0) = r;
    }
  }
  __syncthreads();

  const int h = hg * 4 + (t >> 6), lane = t & 63, quad = lane >> 4, l15 = lane & 15;
  const unsigned short* wf = wfrag + h * 16384 + lane * 8;

  f32x4 acc[4] = {};
  #pragma unroll
  for (int kc = 0; kc < 8; kc++){
    U8 a0, bf[4];
    a0.u = *(const u16x8*)(rex + l15 * 264 + kc * 32 + quad * 8);
    #pragma unroll
    for (int ss = 0; ss < 4; ss++) bf[ss].u = *(const u16x8*)(wf + (kc * 4 + ss) * 512);
    #pragma unroll
    for (int ss = 0; ss < 4; ss++)
      acc[ss] = __builtin_amdgcn_mfma_f32_16x16x32_bf16(a0.b, bf[ss].b, acc[ss], 0, 0, 0);
  }

  // panel store: [b,h,mtile,o(64),m(32)], C/D row(n)=quad*4+i, col(o)=16ss+l15
  {
    const int mtile = tile >> 1, moff = (tile & 1) * 16;
    unsigned short* pan = hT + (size_t)(((b * NH + h) * 32 + mtile) * 64) * 32;
    #pragma unroll
    for (int ss = 0; ss < 4; ss++){
      U4 v;
      v.w[0] = pack_bf16(acc[ss][0], acc[ss][1]);
      v.w[1] = pack_bf16(acc[ss][2], acc[ss][3]);
      *(u16x4*)(pan + (16 * ss + l15) * 32 + moff + quad * 4) = v.u;
    }
  }

  // s/d reductions -> exp tables (R = exp(0.8 s): row factor exp(0.2 s) cancels
  // in softmax, so P' = max(R*Ed, Ed2) gives identical attention weights)
  float as4[4], ad4[4];
  #pragma unroll
  for (int ss = 0; ss < 4; ss++){
    as4[ss] = a_src[h * FO + 16 * ss + l15];
    ad4[ss] = a_dst[h * FO + 16 * ss + l15];
  }
  #pragma unroll
  for (int i = 0; i < 4; i++){
    float ps = 0.f, pd = 0.f;
    #pragma unroll
    for (int ss = 0; ss < 4; ss++){ ps += acc[ss][i] * as4[ss]; pd += acc[ss][i] * ad4[ss]; }
    #pragma unroll
    for (int off = 1; off < 16; off <<= 1){
      ps += __shfl_xor(ps, off);
      pd += __shfl_xor(pd, off);
    }
    if (l15 == 0){
      const int idx = (b * NH + h) * NN + n0 + quad * 4 + i;
      Rt[idx]    = __expf(0.8f * ps);
      expd[idx]  = __expf(pd);
      expd2[idx] = __expf(0.2f * pd);
    }
  }
}

// ---------------------------------------------------------------------------
// Stage B: fused masked-softmax aggregation, ZERO atomics, NO fences.
// (R6 lesson: a per-block __threadfence for cross-XCD visibility costs ~130us
// across 1024 blocks - L2 writeback serializes and evicts the working set.
// Head-merge stays a separate 4us dispatch.)
// 1024 flat blocks of 256 thr; block = 1 head x 64 rows; 4 waves =
// 2 row-halves(rw) x 2 m-halves(mh); 32 rows x 512 cols per wave (2 row-groups
// in-register), 16 fully-unrolled iters (R2-proven inner loop).
// __launch_bounds__(256,4): 128 reg/wave budget (R3 lesson: (256,8) spills).
// XCD decode b=fid&7: panels+Abits+tables L2-resident (R2: FETCH 43->5MB).
// m-halves merge through LDS; denominators per-wave LDS slots; mh=0 waves
// normalize and store per-head hpart coalesced. Head-merge in stageC.
// ---------------------------------------------------------------------------
__global__ __launch_bounds__(256, 4) void attnB(
    const unsigned* __restrict__ Aw,
    const unsigned short* __restrict__ hT,
    const float* __restrict__ Rt,
    const float* __restrict__ expd, const float* __restrict__ expd2,
    float* __restrict__ hpart)
{
  // phase 1: smem[0..1023]=Ed, [1024..2047]=Ed2 (this head)
  // phase 2: smem[0..4159]=merge[64][65], smem[4160..4287]=den[2mh][64]
  __shared__ float smem[4288];
  __shared__ __align__(8) unsigned lut[16][2];   // nibble -> 2 halfword masks

  const int fid = blockIdx.x;
  const int b = fid & 7, h = (fid >> 3) & 7, rt = fid >> 6;  // rt in [0,16)
  const int n0 = rt * 64;

  const int t = threadIdx.x;                     // 256
  const int w = t >> 6, lane = t & 63, quad = lane >> 4, l15 = lane & 15;
  const int rw = w & 1, mh = w >> 1;
  const int nb = n0 + rw * 32;                   // wave's 32-row base

  if (t < 16){
    lut[t][0] = (t & 1 ? 0xFFFFu : 0u) | (t & 2 ? 0xFFFF0000u : 0u);
    lut[t][1] = (t & 4 ? 0xFFFFu : 0u) | (t & 8 ? 0xFFFF0000u : 0u);
  }
  {                                      // exp-table preload (1 head, coalesced)
    const float* s1 = expd  + (b * NH + h) * NN;
    const float* s2 = expd2 + (b * NH + h) * NN;
    *(f32x4*)(smem + t * 4)        = *(const f32x4*)(s1 + t * 4);
    *(f32x4*)(smem + 1024 + t * 4) = *(const f32x4*)(s2 + t * 4);
  }
  __syncthreads();

  const int hb = (b * NH + h) * NN;
  const float Rv0 = Rt[hb + nb + l15];
  const float Rv1 = Rt[hb + nb + 16 + l15];
  const unsigned short* pb = hT + (size_t)(b * NH + h) * 65536 + l15 * 32 + quad * 8;
  const float* edh = smem + quad * 8;
  const float* e2h = smem + 1024 + quad * 8;
  const unsigned* awp = Aw + (b * NN + nb) * 32;
  const int c0 = mh * 16;
  const int qs = quad * 8;

  U8 pan[4];
  #pragma unroll
  for (int ss = 0; ss < 4; ss++)
    pan[ss].u = *(const u16x8*)(pb + (size_t)c0 * 2048 + ss * 512);
  unsigned mw0 = awp[l15 * 32 + c0];
  unsigned mw1 = awp[(16 + l15) * 32 + c0];

  U8 ones;                               // bf16 1.0 B-frag for row sums
  #pragma unroll
  for (int j = 0; j < 8; j++) ones.u[j] = 0x3F80;

  f32x4 acc0[4] = {}, acc1[4] = {};
  f32x4 accl0 = {}, accl1 = {};

  #pragma unroll
  for (int cc = 0; cc < 16; cc++){
    const int c = c0 + cc;
    // expand bit masks via LUT (mask words prefetched last iter)
    const unsigned am0 = (mw0 >> qs) & 0xFF;
    const unsigned am1 = (mw1 >> qs) & 0xFF;
    const uint2 la0 = *(const uint2*)&lut[am0 & 15][0];
    const uint2 lb0 = *(const uint2*)&lut[(am0 >> 4) & 15][0];
    const uint2 la1 = *(const uint2*)&lut[am1 & 15][0];
    const uint2 lb1 = *(const uint2*)&lut[(am1 >> 4) & 15][0];
    if (cc + 1 < 16){                    // mask prefetch from L2 (Abits)
      mw0 = awp[l15 * 32 + c + 1];
      mw1 = awp[(16 + l15) * 32 + c + 1];
    }
    // shared column factors (broadcast LDS reads, conflict-free)
    const f32x4 d01 = *(const f32x4*)(edh + c * 32);
    const f32x4 d23 = *(const f32x4*)(edh + c * 32 + 4);
    const f32x4 g01 = *(const f32x4*)(e2h + c * 32);
    const f32x4 g23 = *(const f32x4*)(e2h + c * 32 + 4);
    // P for row-group 0
    {
      const f32x4 p01 = Rv0 * d01, p23 = Rv0 * d23;
      U8 p;
      p.w[0] = maskpack(fmaxf(p01[0], g01[0]), fmaxf(p01[1], g01[1]), la0.x);
      p.w[1] = maskpack(fmaxf(p01[2], g01[2]), fmaxf(p01[3], g01[3]), la0.y);
      p.w[2] = maskpack(fmaxf(p23[0], g23[0]), fmaxf(p23[1], g23[1]), lb0.x);
      p.w[3] = maskpack(fmaxf(p23[2], g23[2]), fmaxf(p23[3], g23[3]), lb0.y);
      #pragma unroll
      for (int ss = 0; ss < 4; ss++)
        acc0[ss] = __builtin_amdgcn_mfma_f32_16x16x32_bf16(p.b, pan[ss].b, acc0[ss], 0, 0, 0);
      accl0 = __builtin_amdgcn_mfma_f32_16x16x32_bf16(p.b, ones.b, accl0, 0, 0, 0);
    }
    // P for row-group 1 (same pan frags -> panel traffic halved)
    {
      const f32x4 p01 = Rv1 * d01, p23 = Rv1 * d23;
      U8 p;
      p.w[0] = maskpack(fmaxf(p01[0], g01[0]), fmaxf(p01[1], g01[1]), la1.x);
      p.w[1] = maskpack(fmaxf(p01[2], g01[2]), fmaxf(p01[3], g01[3]), la1.y);
      p.w[2] = maskpack(fmaxf(p23[0], g23[0]), fmaxf(p23[1], g23[1]), lb1.x);
      p.w[3] = maskpack(fmaxf(p23[2], g23[2]), fmaxf(p23[3], g23[3]), lb1.y);
      #pragma unroll
      for (int ss = 0; ss < 4; ss++)
        acc1[ss] = __builtin_amdgcn_mfma_f32_16x16x32_bf16(p.b, pan[ss].b, acc1[ss], 0, 0, 0);
      accl1 = __builtin_amdgcn_mfma_f32_16x16x32_bf16(p.b, ones.b, accl1, 0, 0, 0);
    }
    if (cc + 1 < 16){                    // pan prefetch, 1-deep
      #pragma unroll
      for (int ss = 0; ss < 4; ss++)
        pan[ss].u = *(const u16x8*)(pb + (size_t)(c + 1) * 2048 + ss * 512);
    }
  }

  __syncthreads();                       // tables dead; smem becomes merge buffer

  // denominators: accl[i] = complete row sum over this wave's m-half,
  // replicated over l15. Distinct (mh,rw,row) slots -> no atomics.
  float* den = smem + 4160;
  if (l15 == 0){
    #pragma unroll
    for (int i = 0; i < 4; i++){
      den[mh * 64 + rw * 32 + quad * 4 + i]      = accl0[i];
      den[mh * 64 + rw * 32 + 16 + quad * 4 + i] = accl1[i];
    }
  }
  // mh=1 waves park their numerators in merge[64][65]
  if (mh == 1){
    #pragma unroll
    for (int i = 0; i < 4; i++){
      const int r0 = rw * 32 + quad * 4 + i;
      #pragma unroll
      for (int ss = 0; ss < 4; ss++){
        smem[r0 * 65 + ss * 16 + l15]        = acc0[ss][i];
        smem[(r0 + 16) * 65 + ss * 16 + l15] = acc1[ss][i];
      }
    }
  }
  __syncthreads();

  // mh=0 waves: add halves, normalize, plain coalesced store to hpart
  if (mh == 0){
    float* hp = hpart + ((size_t)(b * NH + h) * NN + nb) * FO;
    #pragma unroll
    for (int i = 0; i < 4; i++){
      const int r = quad * 4 + i;
      const float ia = 1.0f / (den[rw * 32 + r] + den[64 + rw * 32 + r]);
      const float ib = 1.0f / (den[rw * 32 + 16 + r] + den[64 + rw * 32 + 16 + r]);
      #pragma unroll
      for (int ss = 0; ss < 4; ss++){
        hp[(size_t)r * FO + ss * 16 + l15] =
            (acc0[ss][i] + smem[(rw * 32 + r) * 65 + ss * 16 + l15]) * ia;
        hp[(size_t)(16 + r) * FO + ss * 16 + l15] =
            (acc1[ss][i] + smem[(rw * 32 + 16 + r) * 65 + ss * 16 + l15]) * ib;
      }
    }
  }
}

// ---------------------------------------------------------------------------
// Stage C: head mean + bias + mask. out = (0.125*sum_h hpart + bias) * mz.
// 16.8 MB streamed reads, 2 MB writes. grid 512 x 256, 4 outputs/thread.
// ---------------------------------------------------------------------------
__global__ __launch_bounds__(256) void stageC(
    const float* __restrict__ hpart, const float* __restrict__ bias,
    const float* __restrict__ mz, float* __restrict__ out)
{
  const int tid = blockIdx.x * 256 + threadIdx.x;    // 131072 threads
  const int o4 = (tid & 15) * 4;
  const int n  = (tid >> 4) & 1023;
  const int b  = tid >> 14;
  const size_t nf = (size_t)n * FO + o4;
  f32x4 s = {};
  #pragma unroll
  for (int h = 0; h < NH; h++)
    s += *(const f32x4*)(hpart + (size_t)(b * NH + h) * NN * FO + nf);
  const f32x4 bv = *(const f32x4*)(bias + o4);
  const float m = mz[b * NN + n];
  f32x4 r;
  #pragma unroll
  for (int j = 0; j < 4; j++) r[j] = (0.125f * s[j] + bv[j]) * m;
  *(f32x4*)(out + (size_t)b * NN * FO + nf) = r;
}

extern "C" void kernel_launch(void* const* d_in, const int* in_sizes, int n_in,
                              void* d_out, int out_size, void* d_ws, size_t ws_size,
                              hipStream_t stream)
{
  (void)in_sizes; (void)n_in; (void)out_size; (void)ws_size;
  const float* x    = (const float*)d_in[0];
  const int*   A    = (const int*)d_in[1];
  const float* mz   = (const float*)d_in[2];
  const float* e_at = (const float*)d_in[4];
  const float* Np   = (const float*)d_in[5];
  const float* w    = (const float*)d_in[6];
  const float* asrc = (const float*)d_in[7];
  const float* adst = (const float*)d_in[8];
  const float* bias = (const float*)d_in[9];
  float* out = (float*)d_out;

  char* ws = (char*)d_ws;
  unsigned short* wfrag = (unsigned short*)ws;                     // 256 KB
  unsigned short* hT    = (unsigned short*)(ws + 262144);          // 8 MB
  float* Rt    = (float*)(ws + 8650752);                           // 256 KB
  float* expd  = (float*)(ws + 8912896);                           // 256 KB
  float* expd2 = (float*)(ws + 9175040);                           // 256 KB
  unsigned long long* Abits = (unsigned long long*)(ws + 9437184); // 1 MB
  float* hpart = (float*)(ws + 10485760);                          // 16.8 MB

  prep <<<dim3(1024), dim3(256), 0, stream>>>(w, A, wfrag, Abits);
  gemmA<<<dim3(1024), dim3(256), 0, stream>>>(x, e_at, Np, wfrag, asrc, adst,
                                              hT, Rt, expd, expd2);
  attnB<<<dim3(1024), dim3(256), 0, stream>>>((const unsigned*)Abits, hT,
                                              Rt, expd, expd2, hpart);
  stageC<<<dim3(512), dim3(256), 0, stream>>>(hpart, bias, mz, out);
}